// Round 1
// baseline (580.243 us; speedup 1.0000x reference)
//
#include <hip/hip_runtime.h>
#include <stdint.h>

#define NNODES 50000
#define NEDGES 800000
#define NHID 96
#define NCLS 16
#define BCAP 64

// ---------- JAX Threefry-2x32 (Random123 20-round, matches jax._src.prng) ----------
__host__ __device__ inline void tf2x32(uint32_t k0, uint32_t k1, uint32_t x0, uint32_t x1,
                                       uint32_t& o0, uint32_t& o1) {
  uint32_t k2 = k0 ^ k1 ^ 0x1BD11BDAu;
#define TFROT(v, r) (((v) << (r)) | ((v) >> (32 - (r))))
#define TFR(r) { x0 += x1; x1 = TFROT(x1, r); x1 ^= x0; }
  x0 += k0; x1 += k1;
  TFR(13) TFR(15) TFR(26) TFR(6)
  x0 += k1; x1 += k2 + 1u;
  TFR(17) TFR(29) TFR(16) TFR(24)
  x0 += k2; x1 += k0 + 2u;
  TFR(13) TFR(15) TFR(26) TFR(6)
  x0 += k0; x1 += k1 + 3u;
  TFR(17) TFR(29) TFR(16) TFR(24)
  x0 += k1; x1 += k2 + 4u;
  TFR(13) TFR(15) TFR(26) TFR(6)
  x0 += k2; x1 += k0 + 5u;
  o0 = x0; o1 = x1;
#undef TFR
#undef TFROT
}

// ---------- degree count + per-dst bucket fill (one pass over edges) ----------
__global__ __launch_bounds__(256) void fill_kernel(
    const int* __restrict__ src, const int* __restrict__ dst, const float* __restrict__ ew,
    int* __restrict__ odeg, int* __restrict__ cursor, int2* __restrict__ bucket) {
  int e = blockIdx.x * 256 + threadIdx.x;
  if (e >= NEDGES) return;
  int s = src[e], d = dst[e];
  atomicAdd(&odeg[s], 1);
  int slot = atomicAdd(&cursor[d], 1);
  if (slot < BCAP)
    bucket[(size_t)d * BCAP + slot] = make_int2(s, __float_as_int(ew[e]));
}

__global__ __launch_bounds__(256) void inv_kernel(
    const int* __restrict__ odeg, const int* __restrict__ ideg,
    float* __restrict__ inv_o, float* __restrict__ inv_i) {
  int n = blockIdx.x * 256 + threadIdx.x;
  if (n >= NNODES) return;
  inv_o[n] = rsqrtf(fmaxf((float)odeg[n], 1.0f));
  inv_i[n] = rsqrtf(fmaxf((float)ideg[n], 1.0f));
}

// ---------- dropout (JAX partitionable threefry bits) + D_out^-1/2 scale ----------
__global__ __launch_bounds__(256) void drop_kernel(
    const float* __restrict__ h, const float* __restrict__ inv_o,
    float* __restrict__ X, uint32_t k0, uint32_t k1) {
  int j = blockIdx.x * 256 + threadIdx.x;
  if (j >= NNODES * NHID) return;
  uint32_t o0, o1;
  tf2x32(k0, k1, 0u, (uint32_t)j, o0, o1);      // counter = uint64 j: hi=0, lo=j
  uint32_t bits = o0 ^ o1;                      // partitionable 32-bit path
  int n = j / NHID;
  // keep iff uniform<0.5 iff MSB==0 ; kept value = h*2*inv_sqrt_out
  float v = ((bits >> 31) == 0u) ? h[j] * (2.0f * inv_o[n]) : 0.0f;
  X[j] = v;
}

// ---------- GEMM: Y[N, OUTD] = X[N, 96] @ W[96, OUTD]; thread = (row, 16 cols) ----------
#define GSTEP(xk, base) { \
  const float4* wr = (const float4*)(base); \
  float4 w0 = wr[0], w1 = wr[1], w2 = wr[2], w3 = wr[3]; \
  acc[0]  += (xk)*w0.x; acc[1]  += (xk)*w0.y; acc[2]  += (xk)*w0.z; acc[3]  += (xk)*w0.w; \
  acc[4]  += (xk)*w1.x; acc[5]  += (xk)*w1.y; acc[6]  += (xk)*w1.z; acc[7]  += (xk)*w1.w; \
  acc[8]  += (xk)*w2.x; acc[9]  += (xk)*w2.y; acc[10] += (xk)*w2.z; acc[11] += (xk)*w2.w; \
  acc[12] += (xk)*w3.x; acc[13] += (xk)*w3.y; acc[14] += (xk)*w3.z; acc[15] += (xk)*w3.w; }

template <int OUTD>
__global__ __launch_bounds__(256) void gemm_kernel(
    const float* __restrict__ X, const float* __restrict__ W, float* __restrict__ Y) {
  constexpr int GROUPS = OUTD / 16;
  int tid = blockIdx.x * 256 + threadIdx.x;
  int r = tid / GROUPS;
  int g = tid - r * GROUPS;
  if (r >= NNODES) return;
  const int c0 = g * 16;
  float acc[16];
#pragma unroll
  for (int i = 0; i < 16; i++) acc[i] = 0.f;
  const float* xrow = X + (size_t)r * 96;
#pragma unroll 2
  for (int kk = 0; kk < 96; kk += 4) {
    float4 x4 = *(const float4*)(xrow + kk);
    GSTEP(x4.x, W + (size_t)(kk + 0) * OUTD + c0)
    GSTEP(x4.y, W + (size_t)(kk + 1) * OUTD + c0)
    GSTEP(x4.z, W + (size_t)(kk + 2) * OUTD + c0)
    GSTEP(x4.w, W + (size_t)(kk + 3) * OUTD + c0)
  }
  float4* yr = (float4*)(Y + (size_t)r * OUTD + c0);
  yr[0] = make_float4(acc[0], acc[1], acc[2], acc[3]);
  yr[1] = make_float4(acc[4], acc[5], acc[6], acc[7]);
  yr[2] = make_float4(acc[8], acc[9], acc[10], acc[11]);
  yr[3] = make_float4(acc[12], acc[13], acc[14], acc[15]);
}

// ---------- per-dst gather of 96-dim messages + inv_in*bias+ReLU epilogue ----------
__global__ __launch_bounds__(256) void gather96_kernel(
    const float* __restrict__ Y, const int2* __restrict__ bucket,
    const int* __restrict__ cnt, const float* __restrict__ inv_in,
    const float* __restrict__ bias, float* __restrict__ hout) {
  int tid = blockIdx.x * 256 + threadIdx.x;
  int n = tid / 24;
  int q = tid - n * 24;        // float4 chunk within the 96-dim row
  if (n >= NNODES) return;
  int c = cnt[n]; if (c > BCAP) c = BCAP;
  const int2* bk = bucket + (size_t)n * BCAP;
  float ax = 0.f, ay = 0.f, az = 0.f, aw = 0.f;
  for (int e = 0; e < c; ++e) {
    int2 pr = bk[e];
    float w = __int_as_float(pr.y);
    float4 v = *(const float4*)(Y + (size_t)pr.x * 96 + q * 4);
    ax += v.x * w; ay += v.y * w; az += v.z * w; aw += v.w * w;
  }
  float iv = inv_in[n];
  float4 bb = *(const float4*)(bias + q * 4);
  float4 o;
  o.x = fmaxf(ax * iv + bb.x, 0.f);
  o.y = fmaxf(ay * iv + bb.y, 0.f);
  o.z = fmaxf(az * iv + bb.z, 0.f);
  o.w = fmaxf(aw * iv + bb.w, 0.f);
  *(float4*)(hout + (size_t)n * 96 + q * 4) = o;
}

// ---------- layer 2: gather 16-dim messages + bias + log_softmax, straight to d_out ----------
__global__ __launch_bounds__(256) void gather16_lsm_kernel(
    const float* __restrict__ Y2, const int2* __restrict__ bucket,
    const int* __restrict__ cnt, const float* __restrict__ inv_in,
    const float* __restrict__ b2, float* __restrict__ out) {
  int n = blockIdx.x * 256 + threadIdx.x;
  if (n >= NNODES) return;
  int c = cnt[n]; if (c > BCAP) c = BCAP;
  const int2* bk = bucket + (size_t)n * BCAP;
  float4 a0 = {0,0,0,0}, a1 = {0,0,0,0}, a2 = {0,0,0,0}, a3 = {0,0,0,0};
  for (int e = 0; e < c; ++e) {
    int2 pr = bk[e];
    float w = __int_as_float(pr.y);
    const float4* y = (const float4*)(Y2 + (size_t)pr.x * 16);
    float4 y0 = y[0], y1 = y[1], y2 = y[2], y3 = y[3];
    a0.x += y0.x * w; a0.y += y0.y * w; a0.z += y0.z * w; a0.w += y0.w * w;
    a1.x += y1.x * w; a1.y += y1.y * w; a1.z += y1.z * w; a1.w += y1.w * w;
    a2.x += y2.x * w; a2.y += y2.y * w; a2.z += y2.z * w; a2.w += y2.w * w;
    a3.x += y3.x * w; a3.y += y3.y * w; a3.z += y3.z * w; a3.w += y3.w * w;
  }
  float iv = inv_in[n];
  float v[16];
  v[0]  = a0.x * iv + b2[0];  v[1]  = a0.y * iv + b2[1];
  v[2]  = a0.z * iv + b2[2];  v[3]  = a0.w * iv + b2[3];
  v[4]  = a1.x * iv + b2[4];  v[5]  = a1.y * iv + b2[5];
  v[6]  = a1.z * iv + b2[6];  v[7]  = a1.w * iv + b2[7];
  v[8]  = a2.x * iv + b2[8];  v[9]  = a2.y * iv + b2[9];
  v[10] = a2.z * iv + b2[10]; v[11] = a2.w * iv + b2[11];
  v[12] = a3.x * iv + b2[12]; v[13] = a3.y * iv + b2[13];
  v[14] = a3.z * iv + b2[14]; v[15] = a3.w * iv + b2[15];
  float m = v[0];
#pragma unroll
  for (int i = 1; i < 16; i++) m = fmaxf(m, v[i]);
  float s = 0.f;
#pragma unroll
  for (int i = 0; i < 16; i++) s += expf(v[i] - m);
  float ls = logf(s);
  float* orow = out + (size_t)n * 16;
#pragma unroll
  for (int i = 0; i < 16; i++) orow[i] = v[i] - m - ls;
}

extern "C" void kernel_launch(void* const* d_in, const int* in_sizes, int n_in,
                              void* d_out, int out_size, void* d_ws, size_t ws_size,
                              hipStream_t stream) {
  const float* feat = (const float*)d_in[0];
  const float* ew   = (const float*)d_in[1];
  const int*   src  = (const int*)d_in[2];
  const int*   dst  = (const int*)d_in[3];
  const float* W0   = (const float*)d_in[4];
  const float* b0   = (const float*)d_in[5];
  const float* W1   = (const float*)d_in[6];
  const float* b1   = (const float*)d_in[7];
  const float* W2   = (const float*)d_in[8];
  const float* b2   = (const float*)d_in[9];
  float* out = (float*)d_out;

  char* base = (char*)d_ws;
  size_t off = 0;
  auto take = [&](size_t nbytes) {
    void* q = base + off;
    off += (nbytes + 255) & ~(size_t)255;
    return q;
  };
  int*   odeg   = (int*)take((size_t)NNODES * 4);
  int*   cursor = (int*)take((size_t)NNODES * 4);   // doubles as in-degree after fill
  float* inv_o  = (float*)take((size_t)NNODES * 4);
  float* inv_i  = (float*)take((size_t)NNODES * 4);
  int2*  bucket = (int2*)take((size_t)NNODES * BCAP * 8);
  float* A      = (float*)take((size_t)NNODES * NHID * 4);
  float* B      = (float*)take((size_t)NNODES * NHID * 4);
  float* Y2     = (float*)take((size_t)NNODES * NCLS * 4);
  (void)ws_size; (void)in_sizes; (void)n_in; (void)out_size;

  // per-layer dropout keys: fold_in(key(42), i) computed on host
  uint32_t k[3][2];
  for (uint32_t i = 0; i < 3; i++) tf2x32(0u, 42u, 0u, i, k[i][0], k[i][1]);

  hipMemsetAsync(odeg,   0, (size_t)NNODES * 4, stream);
  hipMemsetAsync(cursor, 0, (size_t)NNODES * 4, stream);
  fill_kernel<<<(NEDGES + 255) / 256, 256, 0, stream>>>(src, dst, ew, odeg, cursor, bucket);
  inv_kernel<<<(NNODES + 255) / 256, 256, 0, stream>>>(odeg, cursor, inv_o, inv_i);

  const int NELEM = NNODES * NHID;
  // layer 0: feat -> A(dropped) -> B(gemm) -> A(h1)
  drop_kernel<<<(NELEM + 255) / 256, 256, 0, stream>>>(feat, inv_o, A, k[0][0], k[0][1]);
  gemm_kernel<96><<<(NNODES * 6 + 255) / 256, 256, 0, stream>>>(A, W0, B);
  gather96_kernel<<<(NNODES * 24 + 255) / 256, 256, 0, stream>>>(B, bucket, cursor, inv_i, b0, A);
  // layer 1: A -> B -> A -> B(h2)
  drop_kernel<<<(NELEM + 255) / 256, 256, 0, stream>>>(A, inv_o, B, k[1][0], k[1][1]);
  gemm_kernel<96><<<(NNODES * 6 + 255) / 256, 256, 0, stream>>>(B, W1, A);
  gather96_kernel<<<(NNODES * 24 + 255) / 256, 256, 0, stream>>>(A, bucket, cursor, inv_i, b1, B);
  // layer 2: B -> A -> Y2 -> out
  drop_kernel<<<(NELEM + 255) / 256, 256, 0, stream>>>(B, inv_o, A, k[2][0], k[2][1]);
  gemm_kernel<16><<<(NNODES + 255) / 256, 256, 0, stream>>>(A, W2, Y2);
  gather16_lsm_kernel<<<(NNODES + 255) / 256, 256, 0, stream>>>(Y2, bucket, cursor, inv_i, b2, out);
}

// Round 2
// 387.919 us; speedup vs baseline: 1.4958x; 1.4958x over previous
//
#include <hip/hip_runtime.h>
#include <stdint.h>

#define NNODES 50000
#define NEDGES 800000
#define NHID 96
#define NCLS 16
#define BCAP 64

// ---------- JAX Threefry-2x32 (Random123 20-round, matches jax._src.prng) ----------
__host__ __device__ inline void tf2x32(uint32_t k0, uint32_t k1, uint32_t x0, uint32_t x1,
                                       uint32_t& o0, uint32_t& o1) {
  uint32_t k2 = k0 ^ k1 ^ 0x1BD11BDAu;
#define TFROT(v, r) (((v) << (r)) | ((v) >> (32 - (r))))
#define TFR(r) { x0 += x1; x1 = TFROT(x1, r); x1 ^= x0; }
  x0 += k0; x1 += k1;
  TFR(13) TFR(15) TFR(26) TFR(6)
  x0 += k1; x1 += k2 + 1u;
  TFR(17) TFR(29) TFR(16) TFR(24)
  x0 += k2; x1 += k0 + 2u;
  TFR(13) TFR(15) TFR(26) TFR(6)
  x0 += k0; x1 += k1 + 3u;
  TFR(17) TFR(29) TFR(16) TFR(24)
  x0 += k1; x1 += k2 + 4u;
  TFR(13) TFR(15) TFR(26) TFR(6)
  x0 += k2; x1 += k0 + 5u;
  o0 = x0; o1 = x1;
#undef TFR
#undef TFROT
}

// ---------- degree count + per-dst bucket fill (one pass over edges) ----------
__global__ __launch_bounds__(256) void fill_kernel(
    const int* __restrict__ src, const int* __restrict__ dst, const float* __restrict__ ew,
    int* __restrict__ odeg, int* __restrict__ cursor, int2* __restrict__ bucket) {
  int e = blockIdx.x * 256 + threadIdx.x;
  if (e >= NEDGES) return;
  int s = src[e], d = dst[e];
  atomicAdd(&odeg[s], 1);
  int slot = atomicAdd(&cursor[d], 1);
  if (slot < BCAP)
    bucket[(size_t)d * BCAP + slot] = make_int2(s, __float_as_int(ew[e]));
}

__global__ __launch_bounds__(256) void inv_kernel(
    const int* __restrict__ odeg, const int* __restrict__ ideg,
    float* __restrict__ inv_o, float* __restrict__ inv_i) {
  int n = blockIdx.x * 256 + threadIdx.x;
  if (n >= NNODES) return;
  inv_o[n] = rsqrtf(fmaxf((float)odeg[n], 1.0f));
  inv_i[n] = rsqrtf(fmaxf((float)ideg[n], 1.0f));
}

// ---------- dropout (JAX partitionable threefry bits) + D_out^-1/2 scale ----------
__global__ __launch_bounds__(256) void drop_kernel(
    const float* __restrict__ h, const float* __restrict__ inv_o,
    float* __restrict__ X, uint32_t k0, uint32_t k1) {
  int j = blockIdx.x * 256 + threadIdx.x;
  if (j >= NNODES * NHID) return;
  uint32_t o0, o1;
  tf2x32(k0, k1, 0u, (uint32_t)j, o0, o1);      // counter = uint64 j: hi=0, lo=j
  uint32_t bits = o0 ^ o1;                      // partitionable 32-bit path
  int n = j / NHID;
  float v = ((bits >> 31) == 0u) ? h[j] * (2.0f * inv_o[n]) : 0.0f;
  X[j] = v;
}

// ---------- GEMM96: Y[N,96] = X[N,96] @ W[96,96], LDS-staged W ----------
// block = 256 threads: cg = tid&7 (8 col-groups x 12 cols), rq = tid>>3 (32 row-quads x 4 rows)
// block covers 128 rows x 96 cols; thread tile = 4 rows x 12 cols (48 acc).
// LDS W read pattern: dword offset cg*12 mod 32 covers all 32 banks once -> conflict-free broadcast.
__global__ __launch_bounds__(256) void gemm96_kernel(
    const float* __restrict__ X, const float* __restrict__ W, float* __restrict__ Y) {
  __shared__ float Wl[96 * 96];
  const int tid = threadIdx.x;
  {
    const float4* Wg = (const float4*)W;
    float4* Ws = (float4*)Wl;
#pragma unroll
    for (int i = 0; i < 9; ++i)        // 2304 float4 total = 9 * 256
      Ws[tid + i * 256] = Wg[tid + i * 256];
  }
  __syncthreads();

  const int cg = tid & 7;
  const int rq = tid >> 3;
  const int row0 = blockIdx.x * 128 + rq * 4;
  const int c0 = cg * 12;

  float acc[4][12];
#pragma unroll
  for (int r = 0; r < 4; ++r)
#pragma unroll
    for (int c = 0; c < 12; ++c) acc[r][c] = 0.f;

  // clamped row pointers (tail block): loads stay in-bounds, stores guarded below
  const float* xr[4];
#pragma unroll
  for (int r = 0; r < 4; ++r) {
    int rr = row0 + r; if (rr > NNODES - 1) rr = NNODES - 1;
    xr[r] = X + (size_t)rr * 96;
  }

  for (int k = 0; k < 96; k += 4) {
    float4 x4[4];
#pragma unroll
    for (int r = 0; r < 4; ++r) x4[r] = *(const float4*)(xr[r] + k);
#pragma unroll
    for (int kk = 0; kk < 4; ++kk) {
      const float4* wp = (const float4*)(Wl + (k + kk) * 96 + c0);
      float4 w0 = wp[0], w1 = wp[1], w2 = wp[2];
      float xv[4] = { (&x4[0].x)[kk], (&x4[1].x)[kk], (&x4[2].x)[kk], (&x4[3].x)[kk] };
#pragma unroll
      for (int r = 0; r < 4; ++r) {
        acc[r][0]  += xv[r] * w0.x; acc[r][1]  += xv[r] * w0.y;
        acc[r][2]  += xv[r] * w0.z; acc[r][3]  += xv[r] * w0.w;
        acc[r][4]  += xv[r] * w1.x; acc[r][5]  += xv[r] * w1.y;
        acc[r][6]  += xv[r] * w1.z; acc[r][7]  += xv[r] * w1.w;
        acc[r][8]  += xv[r] * w2.x; acc[r][9]  += xv[r] * w2.y;
        acc[r][10] += xv[r] * w2.z; acc[r][11] += xv[r] * w2.w;
      }
    }
  }

#pragma unroll
  for (int r = 0; r < 4; ++r) {
    int rr = row0 + r;
    if (rr < NNODES) {
      float* yp = Y + (size_t)rr * 96 + c0;
      *(float4*)(yp + 0) = make_float4(acc[r][0], acc[r][1], acc[r][2], acc[r][3]);
      *(float4*)(yp + 4) = make_float4(acc[r][4], acc[r][5], acc[r][6], acc[r][7]);
      *(float4*)(yp + 8) = make_float4(acc[r][8], acc[r][9], acc[r][10], acc[r][11]);
    }
  }
}

// ---------- GEMM16: Y[N,16] = X[N,96] @ W[96,16], LDS-staged W ----------
// thread = 2 rows x 16 cols; block 256 threads covers 512 rows.
__global__ __launch_bounds__(256) void gemm16_kernel(
    const float* __restrict__ X, const float* __restrict__ W, float* __restrict__ Y) {
  __shared__ float Wl[96 * 16];
  const int tid = threadIdx.x;
  {
    const float4* Wg = (const float4*)W;
    float4* Ws = (float4*)Wl;
    for (int i = tid; i < 384; i += 256) Ws[i] = Wg[i];
  }
  __syncthreads();

  const int row0 = blockIdx.x * 512 + tid * 2;
  const float* xr[2];
#pragma unroll
  for (int r = 0; r < 2; ++r) {
    int rr = row0 + r; if (rr > NNODES - 1) rr = NNODES - 1;
    xr[r] = X + (size_t)rr * 96;
  }

  float acc[2][16];
#pragma unroll
  for (int r = 0; r < 2; ++r)
#pragma unroll
    for (int c = 0; c < 16; ++c) acc[r][c] = 0.f;

  for (int k = 0; k < 96; k += 4) {
    float4 x4[2];
#pragma unroll
    for (int r = 0; r < 2; ++r) x4[r] = *(const float4*)(xr[r] + k);
#pragma unroll
    for (int kk = 0; kk < 4; ++kk) {
      const float4* wp = (const float4*)(Wl + (k + kk) * 16);
      float4 w0 = wp[0], w1 = wp[1], w2 = wp[2], w3 = wp[3];
#pragma unroll
      for (int r = 0; r < 2; ++r) {
        float xv = (&x4[r].x)[kk];
        acc[r][0]  += xv * w0.x; acc[r][1]  += xv * w0.y;
        acc[r][2]  += xv * w0.z; acc[r][3]  += xv * w0.w;
        acc[r][4]  += xv * w1.x; acc[r][5]  += xv * w1.y;
        acc[r][6]  += xv * w1.z; acc[r][7]  += xv * w1.w;
        acc[r][8]  += xv * w2.x; acc[r][9]  += xv * w2.y;
        acc[r][10] += xv * w2.z; acc[r][11] += xv * w2.w;
        acc[r][12] += xv * w3.x; acc[r][13] += xv * w3.y;
        acc[r][14] += xv * w3.z; acc[r][15] += xv * w3.w;
      }
    }
  }

#pragma unroll
  for (int r = 0; r < 2; ++r) {
    int rr = row0 + r;
    if (rr < NNODES) {
      float4* yp = (float4*)(Y + (size_t)rr * 16);
      yp[0] = make_float4(acc[r][0], acc[r][1], acc[r][2], acc[r][3]);
      yp[1] = make_float4(acc[r][4], acc[r][5], acc[r][6], acc[r][7]);
      yp[2] = make_float4(acc[r][8], acc[r][9], acc[r][10], acc[r][11]);
      yp[3] = make_float4(acc[r][12], acc[r][13], acc[r][14], acc[r][15]);
    }
  }
}

// ---------- per-dst gather of 96-dim messages + inv_in*bias+ReLU epilogue ----------
__global__ __launch_bounds__(256) void gather96_kernel(
    const float* __restrict__ Y, const int2* __restrict__ bucket,
    const int* __restrict__ cnt, const float* __restrict__ inv_in,
    const float* __restrict__ bias, float* __restrict__ hout) {
  int tid = blockIdx.x * 256 + threadIdx.x;
  int n = tid / 24;
  int q = tid - n * 24;        // float4 chunk within the 96-dim row
  if (n >= NNODES) return;
  int c = cnt[n]; if (c > BCAP) c = BCAP;
  const int2* bk = bucket + (size_t)n * BCAP;
  float ax = 0.f, ay = 0.f, az = 0.f, aw = 0.f;
  for (int e = 0; e < c; ++e) {
    int2 pr = bk[e];
    float w = __int_as_float(pr.y);
    float4 v = *(const float4*)(Y + (size_t)pr.x * 96 + q * 4);
    ax += v.x * w; ay += v.y * w; az += v.z * w; aw += v.w * w;
  }
  float iv = inv_in[n];
  float4 bb = *(const float4*)(bias + q * 4);
  float4 o;
  o.x = fmaxf(ax * iv + bb.x, 0.f);
  o.y = fmaxf(ay * iv + bb.y, 0.f);
  o.z = fmaxf(az * iv + bb.z, 0.f);
  o.w = fmaxf(aw * iv + bb.w, 0.f);
  *(float4*)(hout + (size_t)n * 96 + q * 4) = o;
}

// ---------- layer 2: gather 16-dim messages + bias + log_softmax, straight to d_out ----------
__global__ __launch_bounds__(256) void gather16_lsm_kernel(
    const float* __restrict__ Y2, const int2* __restrict__ bucket,
    const int* __restrict__ cnt, const float* __restrict__ inv_in,
    const float* __restrict__ b2, float* __restrict__ out) {
  int n = blockIdx.x * 256 + threadIdx.x;
  if (n >= NNODES) return;
  int c = cnt[n]; if (c > BCAP) c = BCAP;
  const int2* bk = bucket + (size_t)n * BCAP;
  float4 a0 = {0,0,0,0}, a1 = {0,0,0,0}, a2 = {0,0,0,0}, a3 = {0,0,0,0};
  for (int e = 0; e < c; ++e) {
    int2 pr = bk[e];
    float w = __int_as_float(pr.y);
    const float4* y = (const float4*)(Y2 + (size_t)pr.x * 16);
    float4 y0 = y[0], y1 = y[1], y2 = y[2], y3 = y[3];
    a0.x += y0.x * w; a0.y += y0.y * w; a0.z += y0.z * w; a0.w += y0.w * w;
    a1.x += y1.x * w; a1.y += y1.y * w; a1.z += y1.z * w; a1.w += y1.w * w;
    a2.x += y2.x * w; a2.y += y2.y * w; a2.z += y2.z * w; a2.w += y2.w * w;
    a3.x += y3.x * w; a3.y += y3.y * w; a3.z += y3.z * w; a3.w += y3.w * w;
  }
  float iv = inv_in[n];
  float v[16];
  v[0]  = a0.x * iv + b2[0];  v[1]  = a0.y * iv + b2[1];
  v[2]  = a0.z * iv + b2[2];  v[3]  = a0.w * iv + b2[3];
  v[4]  = a1.x * iv + b2[4];  v[5]  = a1.y * iv + b2[5];
  v[6]  = a1.z * iv + b2[6];  v[7]  = a1.w * iv + b2[7];
  v[8]  = a2.x * iv + b2[8];  v[9]  = a2.y * iv + b2[9];
  v[10] = a2.z * iv + b2[10]; v[11] = a2.w * iv + b2[11];
  v[12] = a3.x * iv + b2[12]; v[13] = a3.y * iv + b2[13];
  v[14] = a3.z * iv + b2[14]; v[15] = a3.w * iv + b2[15];
  float m = v[0];
#pragma unroll
  for (int i = 1; i < 16; i++) m = fmaxf(m, v[i]);
  float s = 0.f;
#pragma unroll
  for (int i = 0; i < 16; i++) s += expf(v[i] - m);
  float ls = logf(s);
  float* orow = out + (size_t)n * 16;
#pragma unroll
  for (int i = 0; i < 16; i++) orow[i] = v[i] - m - ls;
}

extern "C" void kernel_launch(void* const* d_in, const int* in_sizes, int n_in,
                              void* d_out, int out_size, void* d_ws, size_t ws_size,
                              hipStream_t stream) {
  const float* feat = (const float*)d_in[0];
  const float* ew   = (const float*)d_in[1];
  const int*   src  = (const int*)d_in[2];
  const int*   dst  = (const int*)d_in[3];
  const float* W0   = (const float*)d_in[4];
  const float* b0   = (const float*)d_in[5];
  const float* W1   = (const float*)d_in[6];
  const float* b1   = (const float*)d_in[7];
  const float* W2   = (const float*)d_in[8];
  const float* b2   = (const float*)d_in[9];
  float* out = (float*)d_out;

  char* base = (char*)d_ws;
  size_t off = 0;
  auto take = [&](size_t nbytes) {
    void* q = base + off;
    off += (nbytes + 255) & ~(size_t)255;
    return q;
  };
  int*   odeg   = (int*)take((size_t)NNODES * 4);
  int*   cursor = (int*)take((size_t)NNODES * 4);   // doubles as in-degree after fill
  float* inv_o  = (float*)take((size_t)NNODES * 4);
  float* inv_i  = (float*)take((size_t)NNODES * 4);
  int2*  bucket = (int2*)take((size_t)NNODES * BCAP * 8);
  float* A      = (float*)take((size_t)NNODES * NHID * 4);
  float* B      = (float*)take((size_t)NNODES * NHID * 4);
  float* Y2     = (float*)take((size_t)NNODES * NCLS * 4);
  (void)ws_size; (void)in_sizes; (void)n_in; (void)out_size;

  // per-layer dropout keys: fold_in(key(42), i) computed on host
  uint32_t k[3][2];
  for (uint32_t i = 0; i < 3; i++) tf2x32(0u, 42u, 0u, i, k[i][0], k[i][1]);

  hipMemsetAsync(odeg,   0, (size_t)NNODES * 4, stream);
  hipMemsetAsync(cursor, 0, (size_t)NNODES * 4, stream);
  fill_kernel<<<(NEDGES + 255) / 256, 256, 0, stream>>>(src, dst, ew, odeg, cursor, bucket);
  inv_kernel<<<(NNODES + 255) / 256, 256, 0, stream>>>(odeg, cursor, inv_o, inv_i);

  const int NELEM = NNODES * NHID;
  const int G96 = (NNODES + 127) / 128;   // 391 blocks
  const int G16 = (NNODES + 511) / 512;   // 98 blocks

  // layer 0: feat -> A(dropped) -> B(gemm) -> A(h1)
  drop_kernel<<<(NELEM + 255) / 256, 256, 0, stream>>>(feat, inv_o, A, k[0][0], k[0][1]);
  gemm96_kernel<<<G96, 256, 0, stream>>>(A, W0, B);
  gather96_kernel<<<(NNODES * 24 + 255) / 256, 256, 0, stream>>>(B, bucket, cursor, inv_i, b0, A);
  // layer 1: A -> B -> A -> B(h2)
  drop_kernel<<<(NELEM + 255) / 256, 256, 0, stream>>>(A, inv_o, B, k[1][0], k[1][1]);
  gemm96_kernel<<<G96, 256, 0, stream>>>(B, W1, A);
  gather96_kernel<<<(NNODES * 24 + 255) / 256, 256, 0, stream>>>(A, bucket, cursor, inv_i, b1, B);
  // layer 2: B -> A -> Y2 -> out
  drop_kernel<<<(NELEM + 255) / 256, 256, 0, stream>>>(B, inv_o, A, k[2][0], k[2][1]);
  gemm16_kernel<<<G16, 256, 0, stream>>>(A, W2, Y2);
  gather16_lsm_kernel<<<(NNODES + 255) / 256, 256, 0, stream>>>(Y2, bucket, cursor, inv_i, b2, out);
}